// Round 1
// baseline (151.008 us; speedup 1.0000x reference)
//
#include <hip/hip_runtime.h>
#include <math.h>

#define ATOM 64

// ---------------------------------------------------------------------------
// MLP head: x[20] -> relu(x@W1+b1) -> relu(h@W2+b2) -> h2@W3  (bias3 added by caller)
// 4 lanes (quad) cooperate: lane j computes h1 outputs [8j,8j+8), then per-lane
// partial products into all 32 h2 pre-activations, quad-butterfly summed.
// All weight reads are LDS float4 (broadcast across the 16 quads of the wave).
// ---------------------------------------------------------------------------
__device__ __forceinline__ float mlp_head(const float* __restrict__ x,
                                          const float* __restrict__ w1, const float* __restrict__ b1,
                                          const float* __restrict__ w2, const float* __restrict__ b2,
                                          const float* __restrict__ w3, int j)
{
    float h1[8];
    {
        float4 ba = *(const float4*)(b1 + 8*j);
        float4 bb = *(const float4*)(b1 + 8*j + 4);
        h1[0]=ba.x; h1[1]=ba.y; h1[2]=ba.z; h1[3]=ba.w;
        h1[4]=bb.x; h1[5]=bb.y; h1[6]=bb.z; h1[7]=bb.w;
    }
#pragma unroll
    for (int d=0; d<20; ++d) {
        float4 w0 = *(const float4*)(w1 + d*32 + 8*j);
        float4 w4 = *(const float4*)(w1 + d*32 + 8*j + 4);
        float xv = x[d];
        h1[0] += xv*w0.x; h1[1] += xv*w0.y; h1[2] += xv*w0.z; h1[3] += xv*w0.w;
        h1[4] += xv*w4.x; h1[5] += xv*w4.y; h1[6] += xv*w4.z; h1[7] += xv*w4.w;
    }
#pragma unroll
    for (int o=0;o<8;++o) h1[o] = fmaxf(h1[o], 0.f);

    float p[32];
#pragma unroll
    for (int q=0;q<32;++q) p[q] = 0.f;
#pragma unroll
    for (int o=0;o<8;++o) {
        const float* row = w2 + (8*j + o)*32;
        float hv = h1[o];
#pragma unroll
        for (int q=0;q<8;++q) {
            float4 w = *(const float4*)(row + 4*q);
            p[4*q+0] += hv*w.x; p[4*q+1] += hv*w.y;
            p[4*q+2] += hv*w.z; p[4*q+3] += hv*w.w;
        }
    }
    // quad reduce all 32 partials -> every lane holds full h2 pre-activation
#pragma unroll
    for (int q=0;q<32;++q) { p[q] += __shfl_xor(p[q],1); p[q] += __shfl_xor(p[q],2); }

    float s = 0.f;
#pragma unroll
    for (int q=0;q<8;++q) {
        float4 bq = *(const float4*)(b2 + 4*q);
        float4 wq = *(const float4*)(w3 + 4*q);
        s += fmaxf(p[4*q+0]+bq.x, 0.f)*wq.x;
        s += fmaxf(p[4*q+1]+bq.y, 0.f)*wq.y;
        s += fmaxf(p[4*q+2]+bq.z, 0.f)*wq.z;
        s += fmaxf(p[4*q+3]+bq.w, 0.f)*wq.w;
    }
    return s;
}

// ---------------------------------------------------------------------------
// Kernel 1: per-action descriptor + both MLP heads + per-block softmax partials
// 4 lanes/action, 16 actions/wave, 64 actions/block.
// Lane j owns atoms [16j, 16j+16): all global loads float4-contiguous.
// ---------------------------------------------------------------------------
__global__ __launch_bounds__(256) void k_main(
    const float* __restrict__ Smat, const float* __restrict__ Rraw, const float* __restrict__ Mspec,
    const float* __restrict__ We1, const float* __restrict__ be1,
    const float* __restrict__ We2, const float* __restrict__ be2,
    const float* __restrict__ Wf1, const float* __restrict__ bf1,
    const float* __restrict__ Wf2, const float* __restrict__ bf2,
    const float* __restrict__ Wf3, const float* __restrict__ bf3,
    const float* __restrict__ Wv1, const float* __restrict__ bv1,
    const float* __restrict__ Wv2, const float* __restrict__ bv2,
    const float* __restrict__ Wv3, const float* __restrict__ bv3,
    float* __restrict__ logits, float* __restrict__ pmax,
    float* __restrict__ psum, float* __restrict__ pval, int n)
{
    __shared__ __align__(16) float4 s_e1[10];     // {b_e1[e], We1[0][e], We1[1][e], We1[2][e]}
    __shared__ __align__(16) float  s_e2[10][12]; // col n: {b_e2[n], We2[0..9][n], pad}
    __shared__ __align__(16) float  s_f1[640], s_v1[640];
    __shared__ __align__(16) float  s_f2[1024], s_v2[1024];
    __shared__ __align__(16) float  s_b1[32], s_b2[32], s_f3[32];
    __shared__ __align__(16) float  s_bv1[32], s_bv2[32], s_v3[32];
    __shared__ float red_l[64], red_v[64];

    const int tid = threadIdx.x;
    for (int i=tid;i<640;i+=256){ s_f1[i]=Wf1[i]; s_v1[i]=Wv1[i]; }
    for (int i=tid;i<1024;i+=256){ s_f2[i]=Wf2[i]; s_v2[i]=Wv2[i]; }
    if (tid<32){ s_b1[tid]=bf1[tid]; s_b2[tid]=bf2[tid]; s_f3[tid]=Wf3[tid];
                 s_bv1[tid]=bv1[tid]; s_bv2[tid]=bv2[tid]; s_v3[tid]=Wv3[tid]; }
    if (tid<10){
        s_e1[tid] = make_float4(be1[tid], We1[tid], We1[10+tid], We1[20+tid]);
        s_e2[tid][0] = be2[tid];
        for (int e=0;e<10;++e) s_e2[tid][1+e] = We2[e*10+tid];
        s_e2[tid][11] = 0.f;
    }
    __syncthreads();

    const int lane = tid & 63;
    const int j    = tid & 3;
    const int grp  = tid >> 2;               // 0..63 : action within block
    const int act  = blockIdx.x*64 + grp;
    const bool active = act < n;
    const int actc = active ? act : (n-1);

    const float*  sp = Smat + (size_t)actc*ATOM;
    const float4* rp = (const float4*)Rraw  + (size_t)actc*ATOM;  // 64 float4/action
    const float4* mp = (const float4*)Mspec + (size_t)actc*48;    // 48 float4/action

    float accA[2][4];
    float accB[4][10];
#pragma unroll
    for (int k=0;k<2;++k)
#pragma unroll
        for (int l=0;l<4;++l) accA[k][l]=0.f;
#pragma unroll
    for (int l=0;l<4;++l)
#pragma unroll
        for (int q=0;q<10;++q) accB[l][q]=0.f;

    float g0[10];
#pragma unroll
    for (int q=0;q<10;++q) g0[q]=0.f;
    float r00=0.f, r01=0.f, r02=0.f, r03=0.f;

    for (int c=0;c<4;++c) {                   // 4 atoms per iteration per lane
        const int a0 = 16*j + 4*c;
        const float4 s4 = *(const float4*)(sp + a0);
        const float4 ra = rp[a0+0];
        const float4 rb = rp[a0+1];
        const float4 rc2= rp[a0+2];
        const float4 rd = rp[a0+3];
        const float4 mA = mp[12*j+3*c+0];
        const float4 mB = mp[12*j+3*c+1];
        const float4 mC = mp[12*j+3*c+2];

        const float sv[4]  = {s4.x,s4.y,s4.z,s4.w};
        const float mk[12] = {mA.x,mA.y,mA.z,mA.w,mB.x,mB.y,mB.z,mB.w,mC.x,mC.y,mC.z,mC.w};
        const float rx[4]  = {ra.x,rb.x,rc2.x,rd.x};
        const float ry[4]  = {ra.y,rb.y,rc2.y,rd.y};
        const float rz[4]  = {ra.z,rb.z,rc2.z,rd.z};
        const float rw[4]  = {ra.w,rb.w,rc2.w,rd.w};

        float R[4][4];
        float h[4][10];
#pragma unroll
        for (int u=0;u<4;++u) {
            const float s = sv[u];
            R[u][0]=s*rx[u]; R[u][1]=s*ry[u]; R[u][2]=s*rz[u]; R[u][3]=s*rw[u];
            const float sg0=s*mk[3*u+0], sg1=s*mk[3*u+1], sg2=s*mk[3*u+2];
#pragma unroll
            for (int e=0;e<10;++e) {
                const float4 w = s_e1[e];
                h[u][e] = fmaxf(0.f, w.x + sg0*w.y + sg1*w.z + sg2*w.w);
            }
        }
#pragma unroll
        for (int q=0;q<10;++q) {
            const float4 c0 = *(const float4*)&s_e2[q][0];
            const float4 c1 = *(const float4*)&s_e2[q][4];
            const float4 c2 = *(const float4*)&s_e2[q][8];
#pragma unroll
            for (int u=0;u<4;++u) {
                float g = c0.x;
                g += h[u][0]*c0.y; g += h[u][1]*c0.z; g += h[u][2]*c0.w;
                g += h[u][3]*c1.x; g += h[u][4]*c1.y; g += h[u][5]*c1.z; g += h[u][6]*c1.w;
                g += h[u][7]*c2.x; g += h[u][8]*c2.y; g += h[u][9]*c2.z;
                accB[0][q] += R[u][0]*g;
                accB[1][q] += R[u][1]*g;
                accB[2][q] += R[u][2]*g;
                accB[3][q] += R[u][3]*g;
                if (q<2) {
                    accA[q][0]+=g*R[u][0]; accA[q][1]+=g*R[u][1];
                    accA[q][2]+=g*R[u][2]; accA[q][3]+=g*R[u][3];
                }
                if (c==0 && u==0) g0[q] = g;  // atom 0 lives on lane j==0 (bcast later)
            }
        }
        if (c==0) { r00=R[0][0]; r01=R[0][1]; r02=R[0][2]; r03=R[0][3]; }
    }

    // quad butterfly-reduce the 48 accumulators (lanes xor 1,2 -> DPP)
#pragma unroll
    for (int k=0;k<2;++k)
#pragma unroll
        for (int l=0;l<4;++l) {
            float v=accA[k][l]; v+=__shfl_xor(v,1); v+=__shfl_xor(v,2); accA[k][l]=v;
        }
#pragma unroll
    for (int l=0;l<4;++l)
#pragma unroll
        for (int q=0;q<10;++q) {
            float v=accB[l][q]; v+=__shfl_xor(v,1); v+=__shfl_xor(v,2); accB[l][q]=v;
        }

    // broadcast atom-0 rank-1 terms from quad lane 0
    const int src = lane & 60;
    float G0[10], R0[4];
#pragma unroll
    for (int q=0;q<10;++q) G0[q] = __shfl(g0[q], src);
    R0[0]=__shfl(r00,src); R0[1]=__shfl(r01,src); R0[2]=__shfl(r02,src); R0[3]=__shfl(r03,src);

    // D = A @ B  (policy head input)
    float Df[20], Dv[20];
#pragma unroll
    for (int k=0;k<2;++k)
#pragma unroll
        for (int q=0;q<10;++q)
            Df[k*10+q] = accA[k][0]*accB[0][q] + accA[k][1]*accB[1][q]
                       + accA[k][2]*accB[2][q] + accA[k][3]*accB[3][q];
    // value head excludes atom 0: subtract its rank-1 contribution, redo D
#pragma unroll
    for (int k=0;k<2;++k)
#pragma unroll
        for (int l=0;l<4;++l) accA[k][l] -= G0[k]*R0[l];
#pragma unroll
    for (int l=0;l<4;++l)
#pragma unroll
        for (int q=0;q<10;++q) accB[l][q] -= R0[l]*G0[q];
#pragma unroll
    for (int k=0;k<2;++k)
#pragma unroll
        for (int q=0;q<10;++q)
            Dv[k*10+q] = accA[k][0]*accB[0][q] + accA[k][1]*accB[1][q]
                       + accA[k][2]*accB[2][q] + accA[k][3]*accB[3][q];

    const float logit = mlp_head(Df, s_f1, s_b1, s_f2, s_b2, s_f3, j) + bf3[0];
    const float vout  = mlp_head(Dv, s_v1, s_bv1, s_v2, s_bv2, s_v3, j) + bv3[0];

    if (j==0) {
        red_l[grp] = active ? logit : -INFINITY;
        red_v[grp] = active ? vout  : 0.f;
        if (active) logits[act] = logit;
    }
    __syncthreads();

    // block softmax/value partials (wave 0, deterministic butterfly)
    if (tid < 64) {
        float m = red_l[tid];
#pragma unroll
        for (int k=1;k<64;k<<=1) m = fmaxf(m, __shfl_xor(m,k));
        float e = expf(red_l[tid] - m);      // -inf -> 0
        float ssum = e, vsum = red_v[tid];
#pragma unroll
        for (int k=1;k<64;k<<=1){ ssum += __shfl_xor(ssum,k); vsum += __shfl_xor(vsum,k); }
        if (tid==0){ pmax[blockIdx.x]=m; psum[blockIdx.x]=ssum; pval[blockIdx.x]=vsum; }
    }
}

// ---------------------------------------------------------------------------
// Kernel 2: merge per-block partials -> logZ, value  (single block, deterministic)
// ---------------------------------------------------------------------------
__global__ __launch_bounds__(256) void k_reduce(const float* __restrict__ pmax,
                                                const float* __restrict__ psum,
                                                const float* __restrict__ pval,
                                                int nb,
                                                float* __restrict__ logZ,
                                                float* __restrict__ value_out)
{
    __shared__ float sm[256];
    const int tid = threadIdx.x;
    float m = -INFINITY;
    for (int i=tid;i<nb;i+=256) m = fmaxf(m, pmax[i]);
    sm[tid]=m; __syncthreads();
    for (int s=128;s>0;s>>=1){ if (tid<s) sm[tid]=fmaxf(sm[tid],sm[tid+s]); __syncthreads(); }
    const float M = sm[0]; __syncthreads();

    float ssum=0.f, vsum=0.f;
    for (int i=tid;i<nb;i+=256){ ssum += psum[i]*expf(pmax[i]-M); vsum += pval[i]; }
    sm[tid]=ssum; __syncthreads();
    for (int s=128;s>0;s>>=1){ if (tid<s) sm[tid]+=sm[tid+s]; __syncthreads(); }
    const float S = sm[0]; __syncthreads();

    sm[tid]=vsum; __syncthreads();
    for (int s=128;s>0;s>>=1){ if (tid<s) sm[tid]+=sm[tid+s]; __syncthreads(); }
    if (tid==0){ *logZ = M + logf(S); *value_out = sm[0]; }
}

// ---------------------------------------------------------------------------
// Kernel 3: apply log-softmax shift
// ---------------------------------------------------------------------------
__global__ __launch_bounds__(256) void k_apply(const float* __restrict__ logits,
                                               const float* __restrict__ logZ,
                                               float* __restrict__ out, int n)
{
    const int i = blockIdx.x*256 + threadIdx.x;
    if (i < n) out[i] = logits[i] - logZ[0];
}

extern "C" void kernel_launch(void* const* d_in, const int* in_sizes, int n_in,
                              void* d_out, int out_size, void* d_ws, size_t ws_size,
                              hipStream_t stream)
{
    const float* Smat  = (const float*)d_in[0];
    const float* Rraw  = (const float*)d_in[1];
    const float* Mspec = (const float*)d_in[2];
    const float* We1 = (const float*)d_in[3];  const float* be1 = (const float*)d_in[4];
    const float* We2 = (const float*)d_in[5];  const float* be2 = (const float*)d_in[6];
    const float* Wf1 = (const float*)d_in[7];  const float* bf1 = (const float*)d_in[8];
    const float* Wf2 = (const float*)d_in[9];  const float* bf2 = (const float*)d_in[10];
    const float* Wf3 = (const float*)d_in[11]; const float* bf3 = (const float*)d_in[12];
    const float* Wv1 = (const float*)d_in[13]; const float* bv1 = (const float*)d_in[14];
    const float* Wv2 = (const float*)d_in[15]; const float* bv2 = (const float*)d_in[16];
    const float* Wv3 = (const float*)d_in[17]; const float* bv3 = (const float*)d_in[18];

    const int n  = in_sizes[0] / ATOM;        // number of actions
    const int nb = (n + 63) / 64;             // blocks (64 actions each)

    float* ws     = (float*)d_ws;
    float* logits = ws;                       // [n]
    float* pmax   = ws + n;                   // [nb]
    float* psum   = pmax + nb;                // [nb]
    float* pval   = psum + nb;                // [nb]
    float* logZ   = pval + nb;                // [1]
    float* out    = (float*)d_out;            // [n] policy, [1] value

    k_main<<<nb, 256, 0, stream>>>(Smat, Rraw, Mspec,
                                   We1, be1, We2, be2,
                                   Wf1, bf1, Wf2, bf2, Wf3, bf3,
                                   Wv1, bv1, Wv2, bv2, Wv3, bv3,
                                   logits, pmax, psum, pval, n);
    k_reduce<<<1, 256, 0, stream>>>(pmax, psum, pval, nb, logZ, out + n);
    k_apply<<<(n + 255)/256, 256, 0, stream>>>(logits, logZ, out, n);
}